// Round 11
// baseline (104.738 us; speedup 1.0000x reference)
//
#include <hip/hip_runtime.h>

constexpr int Bn = 8192;   // batch
constexpr int Dn = 512;    // feature dim
#define EPSF 1e-7f
#define MARGINF 1.0f

using f32x4 = __attribute__((ext_vector_type(4))) float;

__device__ __forceinline__ f32x4 ntload4(const float* p) {
    return __builtin_nontemporal_load((const f32x4*)p);   // streaming load, no cache alloc
}

__device__ __forceinline__ void amax_combine(float& bv, int& bi, float v, int i) {
    // argmax with first-index tie-break (matches jnp.argmax)
    if (v > bv || (v == bv && i < bi)) { bv = v; bi = i; }
}

// ws layout: losses[8192] f32 @0 (32 KB) | packed[2048] u32 @32768 (8 KB)
__global__ __launch_bounds__(256) void pack_labels_kernel(const int* __restrict__ labels,
                                                          unsigned* __restrict__ packed) {
    __shared__ int s_any;
    const int tid = threadIdx.x;
    if (tid == 0) s_any = 0;
    __syncthreads();
    if (tid < 128 && labels[2 * tid + 1] != 0) atomicOr(&s_any, 1);
    __syncthreads();
    const bool is64 = (s_any == 0);   // int64 labels: odd int32 words all zero

    if (is64) {
        const long long* l8 = (const long long*)labels;
        for (int w = tid; w < Bn / 4; w += 256) {
            unsigned b0 = (unsigned)l8[w * 4 + 0] & 0xffu;
            unsigned b1 = (unsigned)l8[w * 4 + 1] & 0xffu;
            unsigned b2 = (unsigned)l8[w * 4 + 2] & 0xffu;
            unsigned b3 = (unsigned)l8[w * 4 + 3] & 0xffu;
            packed[w] = b0 | (b1 << 8) | (b2 << 16) | (b3 << 24);
        }
    } else {
        for (int w = tid; w < Bn / 4; w += 256) {
            int4 v = ((const int4*)labels)[w];
            packed[w] = ((unsigned)v.x & 0xffu) | (((unsigned)v.y & 0xffu) << 8) |
                        (((unsigned)v.z & 0xffu) << 16) | (((unsigned)v.w & 0xffu) << 24);
        }
    }
}

// Block-per-row fused scan (pos+neg argmax) + triplet distance.
// Dense per-wave addressing, fully unrolled -> 16 nt loads in flight.
// XCD-aware swizzle: each XCD processes a contiguous 1024-row chunk.
__global__ __launch_bounds__(256) void triplet_main(
    const float*    __restrict__ feats,
    const unsigned* __restrict__ packed,
    const float*    __restrict__ noise,
    float*          __restrict__ losses)
{
    __shared__ unsigned slab_u[Bn / 4];   // 8 KB packed label bytes
    __shared__ float swv[8];
    __shared__ int   swi[8];
    __shared__ float sdist[8];

    const int bid  = blockIdx.x;
    const int row  = ((bid & 7) << 10) | (bid >> 3);   // XCD-contiguous row mapping
    const int tid  = threadIdx.x;
    const int lane = tid & 63;
    const int wv   = tid >> 6;

    // stage packed labels into LDS (source is L2-hot, 8 KB)
    for (int k = tid; k < Bn / 16; k += 256)
        ((uint4*)slab_u)[k] = ((const uint4*)packed)[k];
    __syncthreads();

    const unsigned myLab = (slab_u[row >> 2] >> ((row & 3) * 8)) & 0xffu;

    const float* __restrict__ n0 = noise + (size_t)row * Bn;
    const float* __restrict__ n1 = noise + (size_t)Bn * Bn + (size_t)row * Bn;

    // 4 independent slot-accumulators break the dependent compare chain.
    float pbv[4] = {-1.0f, -1.0f, -1.0f, -1.0f};
    float nbv[4] = {-1.0f, -1.0f, -1.0f, -1.0f};
    int   pbi[4] = {0x7FFFFFFF, 0x7FFFFFFF, 0x7FFFFFFF, 0x7FFFFFFF};
    int   nbi[4] = {0x7FFFFFFF, 0x7FFFFFFF, 0x7FFFFFFF, 0x7FFFFFFF};

#pragma unroll
    for (int it = 0; it < 8; ++it) {
        const int j = tid * 4 + it * 1024;
        f32x4 v0 = ntload4(n0 + j);
        f32x4 v1 = ntload4(n1 + j);
        unsigned lw = slab_u[j >> 2];
        const float f0[4] = {v0.x, v0.y, v0.z, v0.w};
        const float f1[4] = {v1.x, v1.y, v1.z, v1.w};
#pragma unroll
        for (int k = 0; k < 4; ++k) {
            unsigned lk = (lw >> (k * 8)) & 0xffu;
            // within a slot indices strictly increase -> '>' keeps first max
            float cp = (lk == myLab) ? f0[k] : -1.0f;
            if (cp > pbv[k]) { pbv[k] = cp; pbi[k] = j + k; }
            float cn = (lk != myLab) ? f1[k] : -1.0f;
            if (cn > nbv[k]) { nbv[k] = cn; nbi[k] = j + k; }
        }
    }

    // merge slots (equal values: lower slot = lower index)
    float pv = pbv[0]; int pi_ = pbi[0];
    float nv = nbv[0]; int ni_ = nbi[0];
#pragma unroll
    for (int k = 1; k < 4; ++k) {
        amax_combine(pv, pi_, pbv[k], pbi[k]);
        amax_combine(nv, ni_, nbv[k], nbi[k]);
    }

    // wave-level argmax reduce
    for (int off = 32; off; off >>= 1) {
        float ov = __shfl_down(pv, off, 64);
        int   oi = __shfl_down(pi_, off, 64);
        amax_combine(pv, pi_, ov, oi);
        ov = __shfl_down(nv, off, 64);
        oi = __shfl_down(ni_, off, 64);
        amax_combine(nv, ni_, ov, oi);
    }
    if (lane == 0) { swv[wv] = pv; swi[wv] = pi_; swv[wv + 4] = nv; swi[wv + 4] = ni_; }
    __syncthreads();

    // all threads merge the 4+4 wave partials (uniform result)
    float bv = swv[0]; int bi = swi[0];
#pragma unroll
    for (int k = 1; k < 4; ++k) amax_combine(bv, bi, swv[k], swi[k]);
    float bv2 = swv[4]; int bi2 = swi[4];
#pragma unroll
    for (int k = 5; k < 8; ++k) amax_combine(bv2, bi2, swv[k], swi[k]);
    const int pi = bi;
    const int ni = (bv2 >= 0.0f) ? bi2 : row;   // has_neg fallback -> anchor

    // ---- triplet distances: each thread 2 contiguous floats (feats cached) ----
    const float2 a  = ((const float2*)(feats + (size_t)row * Dn))[tid];
    const float2 p  = ((const float2*)(feats + (size_t)pi  * Dn))[tid];
    const float2 nn = ((const float2*)(feats + (size_t)ni  * Dn))[tid];

    float dx = a.x - p.x + EPSF, dy = a.y - p.y + EPSF;
    float dap = dx * dx + dy * dy;
    dx = a.x - nn.x + EPSF; dy = a.y - nn.y + EPSF;
    float dan = dx * dx + dy * dy;

    for (int off = 32; off; off >>= 1) {
        dap += __shfl_down(dap, off, 64);
        dan += __shfl_down(dan, off, 64);
    }
    if (lane == 0) { sdist[wv] = dap; sdist[wv + 4] = dan; }
    __syncthreads();

    if (tid == 0) {
        float sap = sdist[0] + sdist[1] + sdist[2] + sdist[3];
        float san = sdist[4] + sdist[5] + sdist[6] + sdist[7];
        losses[row] = fmaxf(sqrtf(sap) - sqrtf(san) + MARGINF, 0.0f);
    }
}

// deterministic mean over Bn losses, single block
__global__ __launch_bounds__(256) void reduce_mean_kernel(
    const float* __restrict__ losses, float* __restrict__ out)
{
    const int tid  = threadIdx.x;
    const int lane = tid & 63;
    const int wv   = tid >> 6;
    float s = 0.0f;
    for (int k = tid; k < Bn; k += 256) s += losses[k];
    for (int off = 32; off; off >>= 1) s += __shfl_down(s, off, 64);
    __shared__ float sw[4];
    if (lane == 0) sw[wv] = s;
    __syncthreads();
    if (tid == 0) out[0] = (sw[0] + sw[1] + sw[2] + sw[3]) * (1.0f / (float)Bn);
}

extern "C" void kernel_launch(void* const* d_in, const int* in_sizes, int n_in,
                              void* d_out, int out_size, void* d_ws, size_t ws_size,
                              hipStream_t stream) {
    const float* feats  = (const float*)d_in[0];
    const int*   labels = (const int*)d_in[1];
    const float* noise  = (const float*)d_in[2];

    float*    losses = (float*)d_ws;                       // 32 KB
    unsigned* packed = (unsigned*)((char*)d_ws + 32768);   // 8 KB

    pack_labels_kernel<<<1, 256, 0, stream>>>(labels, packed);
    triplet_main<<<Bn, 256, 0, stream>>>(feats, packed, noise, losses);
    reduce_mean_kernel<<<1, 256, 0, stream>>>(losses, (float*)d_out);
}